// Round 8
// baseline (717.849 us; speedup 1.0000x reference)
//
#include <hip/hip_runtime.h>
#include <cmath>

namespace {

constexpr int N = 100000;
constexpr int E = 1600000;
constexpr int S = 32;           // hidden
constexpr int L = 5;            // layers
constexpr int NB = (N + 255) / 256;   // node-per-thread kernels
constexpr int NPW = 16;               // nodes per wave in layer kernel
constexpr int LB2 = (N + 63) / 64;    // 1563 blocks (4 waves/block, 16 nodes/wave)
constexpr float PI_F    = 3.14159265358979323846f;
constexpr float SQRT2_F = 1.41421356237309515f;

typedef __attribute__((ext_vector_type(8))) short short8;   // 8 x bf16
typedef __attribute__((ext_vector_type(4))) float f32x4;

__device__ __forceinline__ float silu_f(float x) {
    return x / (1.0f + __expf(-x));
}

// float -> bf16 bits, round-to-nearest-even
__device__ __forceinline__ unsigned short f2bf(float f) {
    unsigned int u = __float_as_uint(f);
    u = (u + 0x7FFFu + ((u >> 16) & 1u)) >> 16;
    return (unsigned short)u;
}

__device__ __forceinline__ int rl(int v, int i) {
    return __builtin_amdgcn_readlane(v, i);
}

// advance (i,t) to the next tile of this wave's 16-node batch (uniform)
__device__ __forceinline__ void adv(int& i, int& t, int vd) {
    ++t;
    while (i < 16) {
        int dgi = rl(vd, i);
        int nt = (dgi + 15) >> 4;
        if (t < nt) break;
        t = 0; ++i;
    }
}

// CSR slot for (i,t) at lane row ml; clamped into the node's own range
__device__ __forceinline__ int slotOf(int i, int t, int vs, int vd, int ml) {
    if (i >= 16) return 0;
    int s0 = rl(vs, i);
    int dg = rl(vd, i);
    int smax = s0 + ((dg > 0) ? dg : 1) - 1;
    int s = s0 + t * 16 + ml;
    return min(s, smax);
}

// ---------------------------------------------------------------- degree count
__global__ __launch_bounds__(256) void deg_kernel(
    const int* __restrict__ ei, int* __restrict__ deg)
{
    int e = blockIdx.x * 256 + threadIdx.x;
    if (e >= E) return;
    atomicAdd(&deg[ei[e]], 1);
}

// ---------------------------------------------------------------- scan (3-kernel hierarchical)
__global__ __launch_bounds__(256) void scanA(
    const int* __restrict__ deg, int* __restrict__ bsum)
{
    __shared__ int sd[256];
    int t = threadIdx.x;
    int n = blockIdx.x * 256 + t;
    sd[t] = (n < N) ? deg[n] : 0;
    __syncthreads();
    #pragma unroll
    for (int s = 128; s > 0; s >>= 1) {
        if (t < s) sd[t] += sd[t + s];
        __syncthreads();
    }
    if (t == 0) bsum[blockIdx.x] = sd[0];
}

__global__ __launch_bounds__(512) void scanB(int* __restrict__ bsum)
{
    __shared__ int sd[512];
    int t = threadIdx.x;
    sd[t] = (t < NB) ? bsum[t] : 0;
    __syncthreads();
    #pragma unroll
    for (int off = 1; off < 512; off <<= 1) {
        int v = (t >= off) ? sd[t - off] : 0;
        __syncthreads();
        sd[t] += v;
        __syncthreads();
    }
    if (t < NB) bsum[t] = (t == 0) ? 0 : sd[t - 1];   // exclusive
}

__global__ __launch_bounds__(256) void scanC(
    const int* __restrict__ deg, const int* __restrict__ bsum,
    int* __restrict__ start)
{
    __shared__ int sd[256];
    int t = threadIdx.x;
    int n = blockIdx.x * 256 + t;
    int v = (n < N) ? deg[n] : 0;
    sd[t] = v;
    __syncthreads();
    #pragma unroll
    for (int off = 1; off < 256; off <<= 1) {
        int w = (t >= off) ? sd[t - off] : 0;
        __syncthreads();
        sd[t] += w;
        __syncthreads();
    }
    if (n < N) start[n] = bsum[blockIdx.x] + sd[t] - v;  // exclusive
}

// ---------------------------------------------------------------- CSR fill (8B scatter only)
__global__ __launch_bounds__(256) void fill_kernel(
    const int* __restrict__ ei, const float* __restrict__ pos,
    const int* __restrict__ start, int* __restrict__ cursor,
    int* __restrict__ csr_col, float* __restrict__ csr_dist)
{
    int e = blockIdx.x * 256 + threadIdx.x;
    if (e >= E) return;
    int r = ei[e];
    int c = ei[E + e];
    float2 pr = reinterpret_cast<const float2*>(pos)[r];
    float2 pc = reinterpret_cast<const float2*>(pos)[c];
    float dx = pr.x - pc.x, dy = pr.y - pc.y;
    float d = sqrtf(dx * dx + dy * dy);   // pos-mean cancels
    int k = atomicAdd(&cursor[r], 1);
    int s = start[r] + k;
    csr_col[s] = c;
    csr_dist[s] = d;
}

// ---------------------------------------------------------------- rbf build (fully coalesced)
__global__ __launch_bounds__(256) void rbf_kernel(
    const float* __restrict__ csr_dist, unsigned short* __restrict__ rbf_buf)
{
    int s = blockIdx.x * 256 + threadIdx.x;
    if (s >= E) return;
    float d = csr_dist[s];

    float s1 = __sinf(PI_F * d);
    float c1 = __cosf(PI_F * d);
    float inv = SQRT2_F / (d + 1e-8f);
    float tc = 2.0f * c1;
    float sk = s1, skm = 0.0f;
    unsigned int pk[8];
    #pragma unroll
    for (int i = 0; i < 8; ++i) {
        float r0 = sk * inv;
        float s2 = tc * sk - skm; skm = sk; sk = s2;
        float r1 = sk * inv;
        float s3 = tc * sk - skm; skm = sk; sk = s3;
        pk[i] = (unsigned int)f2bf(r0) | ((unsigned int)f2bf(r1) << 16);
    }
    uint4* out = reinterpret_cast<uint4*>(rbf_buf + (size_t)s * 16);
    out[0] = make_uint4(pk[0], pk[1], pk[2], pk[3]);
    out[1] = make_uint4(pk[4], pk[5], pk[6], pk[7]);
}

// ---------------------------------------------------------------- bf16 weight prep (transposed [n][k])
__global__ __launch_bounds__(256) void prep_wt_kernel(
    const float* __restrict__ We1, const float* __restrict__ We2,
    const float* __restrict__ Wu1, const float* __restrict__ Wu2,
    short* __restrict__ wt1, short* __restrict__ wt2,
    short* __restrict__ wtu1, short* __restrict__ wtu2)
{
    int idx = blockIdx.x * 256 + threadIdx.x;
    if (idx < 5 * 32 * 96) {
        int l = idx / (32 * 96), r = idx % (32 * 96), n = r / 96, k = r % 96;
        float v = (k < 80) ? We1[((size_t)l * 80 + k) * 32 + n] : 0.0f;
        wt1[idx] = (short)f2bf(v);
    }
    if (idx < 5 * 32 * 32) {
        int l = idx / 1024, r = idx % 1024, n = r / 32, k = r % 32;
        wt2[idx]  = (short)f2bf(We2[((size_t)l * 32 + k) * 32 + n]);
        wtu2[idx] = (short)f2bf(Wu2[((size_t)l * 32 + k) * 32 + n]);
    }
    if (idx < 5 * 32 * 64) {
        int l = idx / 2048, r = idx % 2048, n = r / 64, k = r % 64;
        wtu1[idx] = (short)f2bf(Wu1[((size_t)l * 64 + k) * 32 + n]);
    }
}

// ---------------------------------------------------------------- node embed (writes fp32 x + bf16 xb)
__global__ __launch_bounds__(256) void node_embed_kernel(
    const float* __restrict__ u, const float* __restrict__ v,
    const float* __restrict__ bnorm, const float* __restrict__ yf,
    const float* __restrict__ Wn1, const float* __restrict__ bn1,
    const float* __restrict__ Wn2, const float* __restrict__ bn2,
    float* __restrict__ x, unsigned short* __restrict__ xb)
{
    int n = blockIdx.x * 256 + threadIdx.x;
    if (n >= N) return;

    float f[10];
    float4 uu = reinterpret_cast<const float4*>(u)[n];
    f[0] = uu.x; f[1] = uu.y; f[2] = uu.z; f[3] = uu.w;
    float4 v0 = reinterpret_cast<const float4*>(v)[2 * n];
    float4 v1 = reinterpret_cast<const float4*>(v)[2 * n + 1];
    f[4] = sqrtf(v0.x * v0.x + v0.y * v0.y);
    f[5] = sqrtf(v0.z * v0.z + v0.w * v0.w);
    f[6] = sqrtf(v1.x * v1.x + v1.y * v1.y);
    f[7] = sqrtf(v1.z * v1.z + v1.w * v1.w);
    float2 bb = reinterpret_cast<const float2*>(bnorm)[n];
    f[8] = sqrtf(bb.x * bb.x + bb.y * bb.y);
    float2 yy = reinterpret_cast<const float2*>(yf)[n];
    f[9] = sqrtf(yy.x * yy.x + yy.y * yy.y);

    float h[64];
    #pragma unroll
    for (int j = 0; j < 64; ++j) h[j] = bn1[j];
    #pragma unroll
    for (int i = 0; i < 10; ++i) {
        float t = f[i];
        #pragma unroll
        for (int j = 0; j < 64; ++j) h[j] = fmaf(t, Wn1[i * 64 + j], h[j]);
    }
    #pragma unroll
    for (int j = 0; j < 64; ++j) h[j] = silu_f(h[j]);

    float o[32];
    #pragma unroll
    for (int j = 0; j < 32; ++j) o[j] = bn2[j];
    #pragma unroll
    for (int i = 0; i < 64; ++i) {
        float t = h[i];
        #pragma unroll
        for (int j = 0; j < 32; ++j) o[j] = fmaf(t, Wn2[i * 32 + j], o[j]);
    }
    float4* xo = reinterpret_cast<float4*>(x + (size_t)n * 32);
    #pragma unroll
    for (int i = 0; i < 8; ++i)
        xo[i] = make_float4(o[4 * i], o[4 * i + 1], o[4 * i + 2], o[4 * i + 3]);

    unsigned int* xbu = reinterpret_cast<unsigned int*>(xb) + (size_t)n * 16;
    #pragma unroll
    for (int i = 0; i < 16; ++i)
        xbu[i] = (unsigned int)f2bf(o[2 * i]) | ((unsigned int)f2bf(o[2 * i + 1]) << 16);
}

// ---------------------------------------------------------------- fused layer v3
// One wave = 16 consecutive nodes. Edge phase: per-node 16-edge MFMA tiles, 2-deep
// software pipeline. Node phase: 8 MFMAs with bf16 LDS hops. Residual x read from
// global in epilogue (no fp32 LDS stage). launch_bounds(256,6) -> 24 waves/CU.
__global__ __launch_bounds__(256, 6) void layer_kernel(
    const int* __restrict__ deg, const int* __restrict__ start,
    const int* __restrict__ csr_col, const unsigned short* __restrict__ rbf_buf,
    const float* __restrict__ x_in, const unsigned short* __restrict__ xb_in,
    float* __restrict__ x_out, unsigned short* __restrict__ xb_out,
    const short* __restrict__ wt1, const float* __restrict__ b1,
    const short* __restrict__ wt2, const float* __restrict__ b2,
    const short* __restrict__ wtu1, const float* __restrict__ bu1,
    const short* __restrict__ wtu2, const float* __restrict__ bu2)
{
    __shared__ unsigned short lsh[4][16 * 34];   // sh  (bf16), stride 34
    __shared__ unsigned short agb[4][16 * 34];   // ag  (bf16)
    __shared__ unsigned short hub[4][16 * 34];   // hu  (bf16)
    __shared__ float ldg[4][16];
    __shared__ float livd[4][16];

    int t = threadIdx.x;
    int w = t >> 6;
    int lane = t & 63;
    int quad = lane >> 4;
    int ml = lane & 15;
    int wid = blockIdx.x * 4 + w;
    int nbase = __builtin_amdgcn_readfirstlane(wid * NPW);
    if (nbase >= N) return;   // N % 16 == 0, so valid waves own full batches

    // ---- batch metadata: lane ml holds node ml's start/deg
    int vs = start[nbase + ml];
    int vd = deg[nbase + ml];

    // ---- edge-phase B fragments (wt1 [32][96])
    const short8* wp = reinterpret_cast<const short8*>(wt1);
    short8 B00 = wp[(ml     ) * 12 + 0 * 4 + quad];
    short8 B01 = wp[(ml     ) * 12 + 1 * 4 + quad];
    short8 B02 = wp[(ml     ) * 12 + 2 * 4 + quad];
    short8 B10 = wp[(ml + 16) * 12 + 0 * 4 + quad];
    short8 B11 = wp[(ml + 16) * 12 + 1 * 4 + quad];
    short8 B12 = wp[(ml + 16) * 12 + 2 * 4 + quad];

    const short8* xbp = reinterpret_cast<const short8*>(xb_in);
    // node-phase x A-fragment (A[m=node ml][k=quad*8+j]) — prefetch now
    short8 Ax = xbp[(size_t)(nbase + ml) * 4 + quad];

    float b1j0 = b1[ml];
    float b1j1 = b1[ml + 16];

    // ---- zero sh (covers deg==0 nodes), stash deg floats
    unsigned short* lshp = lsh[w];
    for (int k = lane; k < 16 * 34; k += 64) lshp[k] = 0;
    if (lane < 16) {
        ldg[w][lane] = (float)vd;
        livd[w][lane] = 1.0f / fmaxf((float)vd, 1.0f);
    }

    // ---- software-pipelined edge loop
    const short8 Z8 = {0, 0, 0, 0, 0, 0, 0, 0};
    int i0 = 0, t0 = -1; adv(i0, t0, vd);
    int i1 = i0, t1 = t0; adv(i1, t1, vd);
    int i2 = i1, t2 = t1; adv(i2, t2, vd);

    int slot0 = slotOf(i0, t0, vs, vd, ml);
    int slot1 = slotOf(i1, t1, vs, vd, ml);
    int colCur  = csr_col[slot0];
    int colNext = csr_col[slot1];
    short8 A1c = xbp[(size_t)colCur * 4 + quad];
    short8 A2c = Z8;
    if (quad < 2) A2c = *reinterpret_cast<const short8*>(rbf_buf + (size_t)slot0 * 16 + quad * 8);
    short8 A0c = xbp[(size_t)(nbase + min(i0, 15)) * 4 + quad];

    float colp0 = 0.0f, colp1 = 0.0f;
    while (i0 < 16) {
        // stage 2: col two ahead
        int slot2 = slotOf(i2, t2, vs, vd, ml);
        int colNN = csr_col[slot2];
        // stage 1: fragments one ahead
        short8 A1n = xbp[(size_t)colNext * 4 + quad];
        short8 A2n = Z8;
        if (quad < 2) A2n = *reinterpret_cast<const short8*>(rbf_buf + (size_t)slot1 * 16 + quad * 8);
        short8 A0n = xbp[(size_t)(nbase + min(i1, 15)) * 4 + quad];

        // stage 0: compute current tile
        f32x4 acc0 = {0.0f, 0.0f, 0.0f, 0.0f};
        f32x4 acc1 = {0.0f, 0.0f, 0.0f, 0.0f};
        acc0 = __builtin_amdgcn_mfma_f32_16x16x32_bf16(A0c, B00, acc0, 0, 0, 0);
        acc0 = __builtin_amdgcn_mfma_f32_16x16x32_bf16(A1c, B01, acc0, 0, 0, 0);
        acc0 = __builtin_amdgcn_mfma_f32_16x16x32_bf16(A2c, B02, acc0, 0, 0, 0);
        acc1 = __builtin_amdgcn_mfma_f32_16x16x32_bf16(A0c, B10, acc1, 0, 0, 0);
        acc1 = __builtin_amdgcn_mfma_f32_16x16x32_bf16(A1c, B11, acc1, 0, 0, 0);
        acc1 = __builtin_amdgcn_mfma_f32_16x16x32_bf16(A2c, B12, acc1, 0, 0, 0);

        int dg0 = rl(vd, i0);
        int rowbase = t0 * 16 + quad * 4;
        #pragma unroll
        for (int r = 0; r < 4; ++r) {
            bool vld = (rowbase + r) < dg0;
            float h0 = acc0[r] + b1j0;
            float h1 = acc1[r] + b1j1;
            colp0 += vld ? silu_f(h0) : 0.0f;
            colp1 += vld ? silu_f(h1) : 0.0f;
        }
        if (t0 == ((dg0 + 15) >> 4) - 1) {   // last tile of node i0 (uniform)
            colp0 += __shfl_xor(colp0, 16, 64);
            colp0 += __shfl_xor(colp0, 32, 64);
            colp1 += __shfl_xor(colp1, 16, 64);
            colp1 += __shfl_xor(colp1, 32, 64);
            if (quad == 0) {
                lshp[i0 * 34 + ml]      = f2bf(colp0);
                lshp[i0 * 34 + ml + 16] = f2bf(colp1);
            }
            colp0 = 0.0f; colp1 = 0.0f;
        }

        // rotate pipeline
        A0c = A0n; A1c = A1n; A2c = A2n;
        colNext = colNN; slot1 = slot2;
        i0 = i1; t0 = t1; i1 = i2; t1 = t2;
        adv(i2, t2, vd);
    }
    __builtin_amdgcn_wave_barrier();

    // ---- prefetch residual x (latency overlaps node-phase MFMAs)
    int row = quad * 4;
    float xr0[4], xr1[4];
    #pragma unroll
    for (int r = 0; r < 4; ++r) {
        const float* xp = x_in + (size_t)(nbase + row + r) * 32;
        xr0[r] = xp[ml];
        xr1[r] = xp[ml + 16];
    }

    // ---- node phase: 16-node batch, 8 MFMAs
    const short8* w2p = reinterpret_cast<const short8*>(wt2);
    short8 Bw2_0 = w2p[(ml     ) * 4 + quad];
    short8 Bw2_1 = w2p[(ml + 16) * 4 + quad];
    const short8* u1p = reinterpret_cast<const short8*>(wtu1);
    short8 Bu1_00 = u1p[(ml     ) * 8 + quad];       // k 0..31 (x)
    short8 Bu1_10 = u1p[(ml     ) * 8 + 4 + quad];   // k 32..63 (ag)
    short8 Bu1_01 = u1p[(ml + 16) * 8 + quad];
    short8 Bu1_11 = u1p[(ml + 16) * 8 + 4 + quad];
    const short8* u2p = reinterpret_cast<const short8*>(wtu2);
    short8 Bu2_0 = u2p[(ml     ) * 4 + quad];
    short8 Bu2_1 = u2p[(ml + 16) * 4 + quad];

    // sh @ W2
    short8 Ash = *reinterpret_cast<const short8*>(lshp + ml * 34 + quad * 8);
    f32x4 c0 = {0.0f, 0.0f, 0.0f, 0.0f};
    f32x4 c1 = {0.0f, 0.0f, 0.0f, 0.0f};
    c0 = __builtin_amdgcn_mfma_f32_16x16x32_bf16(Ash, Bw2_0, c0, 0, 0, 0);
    c1 = __builtin_amdgcn_mfma_f32_16x16x32_bf16(Ash, Bw2_1, c1, 0, 0, 0);
    float b2c0 = b2[ml], b2c1 = b2[ml + 16];
    unsigned short* agp = agb[w];
    #pragma unroll
    for (int r = 0; r < 4; ++r) {
        float fd = ldg[w][row + r];
        float iv = livd[w][row + r];
        agp[(row + r) * 34 + ml]      = f2bf((c0[r] + fd * b2c0) * iv);
        agp[(row + r) * 34 + ml + 16] = f2bf((c1[r] + fd * b2c1) * iv);
    }
    __builtin_amdgcn_wave_barrier();

    // [x ; ag] @ Wu1
    short8 Aag = *reinterpret_cast<const short8*>(agp + ml * 34 + quad * 8);
    f32x4 d0 = {0.0f, 0.0f, 0.0f, 0.0f};
    f32x4 d1 = {0.0f, 0.0f, 0.0f, 0.0f};
    d0 = __builtin_amdgcn_mfma_f32_16x16x32_bf16(Ax,  Bu1_00, d0, 0, 0, 0);
    d0 = __builtin_amdgcn_mfma_f32_16x16x32_bf16(Aag, Bu1_10, d0, 0, 0, 0);
    d1 = __builtin_amdgcn_mfma_f32_16x16x32_bf16(Ax,  Bu1_01, d1, 0, 0, 0);
    d1 = __builtin_amdgcn_mfma_f32_16x16x32_bf16(Aag, Bu1_11, d1, 0, 0, 0);
    float bu1c0 = bu1[ml], bu1c1 = bu1[ml + 16];
    unsigned short* hup = hub[w];
    #pragma unroll
    for (int r = 0; r < 4; ++r) {
        hup[(row + r) * 34 + ml]      = f2bf(silu_f(d0[r] + bu1c0));
        hup[(row + r) * 34 + ml + 16] = f2bf(silu_f(d1[r] + bu1c1));
    }
    __builtin_amdgcn_wave_barrier();

    // hu @ Wu2 ; residual + store
    short8 Ahu = *reinterpret_cast<const short8*>(hup + ml * 34 + quad * 8);
    f32x4 e0 = {0.0f, 0.0f, 0.0f, 0.0f};
    f32x4 e1 = {0.0f, 0.0f, 0.0f, 0.0f};
    e0 = __builtin_amdgcn_mfma_f32_16x16x32_bf16(Ahu, Bu2_0, e0, 0, 0, 0);
    e1 = __builtin_amdgcn_mfma_f32_16x16x32_bf16(Ahu, Bu2_1, e1, 0, 0, 0);
    float bu2c0 = bu2[ml], bu2c1 = bu2[ml + 16];
    #pragma unroll
    for (int r = 0; r < 4; ++r) {
        int nn = nbase + row + r;
        float o0 = e0[r] + bu2c0 + xr0[r];
        float o1 = e1[r] + bu2c1 + xr1[r];
        x_out[(size_t)nn * 32 + ml]      = o0;
        x_out[(size_t)nn * 32 + ml + 16] = o1;
        xb_out[(size_t)nn * 32 + ml]      = f2bf(o0);
        xb_out[(size_t)nn * 32 + ml + 16] = f2bf(o1);
    }
}

// ---------------------------------------------------------------- LN + heads
__global__ __launch_bounds__(256) void final_kernel(
    const float* __restrict__ x, const float* __restrict__ u,
    const float* __restrict__ v,
    const float* __restrict__ ln_g, const float* __restrict__ ln_b,
    const float* __restrict__ Wr1, const float* __restrict__ br1,
    const float* __restrict__ Wr2, const float* __restrict__ br2,
    const float* __restrict__ Ws1, const float* __restrict__ bs1,
    const float* __restrict__ Ws2, const float* __restrict__ bs2,
    float* __restrict__ out)
{
    int n = blockIdx.x * 256 + threadIdx.x;
    if (n >= N) return;

    float a[32];
    const float4* x4 = reinterpret_cast<const float4*>(x + (size_t)n * 32);
    #pragma unroll
    for (int i = 0; i < 8; ++i) {
        float4 t = x4[i];
        a[4 * i] = t.x; a[4 * i + 1] = t.y; a[4 * i + 2] = t.z; a[4 * i + 3] = t.w;
    }
    float mu = 0.0f;
    #pragma unroll
    for (int i = 0; i < 32; ++i) mu += a[i];
    mu *= (1.0f / 32.0f);
    float var = 0.0f;
    #pragma unroll
    for (int i = 0; i < 32; ++i) { float dlt = a[i] - mu; var += dlt * dlt; }
    var *= (1.0f / 32.0f);
    float rs = rsqrtf(var + 1e-5f);
    #pragma unroll
    for (int i = 0; i < 32; ++i) a[i] = (a[i] - mu) * rs * ln_g[i] + ln_b[i];

    float o0 = br2[0], o1 = br2[1], o2 = bs2[0];
    #pragma unroll 1
    for (int j = 0; j < 96; ++j) {
        float hr = br1[j];
        float hs = bs1[j];
        #pragma unroll
        for (int i = 0; i < 32; ++i) {
            hr = fmaf(a[i], Wr1[i * 96 + j], hr);
            hs = fmaf(a[i], Ws1[i * 96 + j], hs);
        }
        hr = silu_f(hr);
        hs = silu_f(hs);
        o0 = fmaf(hr, Wr2[2 * j], o0);
        o1 = fmaf(hr, Wr2[2 * j + 1], o1);
        o2 = fmaf(hs, Ws2[j], o2);
    }
    out[n] = u[n * 4 + 3] + o2;
    out[N + 2 * n]     = o0 + v[n * 8 + 6];
    out[N + 2 * n + 1] = o1 + v[n * 8 + 7];
}

} // anonymous namespace

extern "C" void kernel_launch(void* const* d_in, const int* in_sizes, int n_in,
                              void* d_out, int out_size, void* d_ws, size_t ws_size,
                              hipStream_t stream)
{
    const float* u    = (const float*)d_in[0];
    const float* v    = (const float*)d_in[1];
    const float* bno  = (const float*)d_in[2];
    const float* yf   = (const float*)d_in[4];
    const float* pos  = (const float*)d_in[5];
    const int*   ei   = (const int*)d_in[6];
    const float* Wn1  = (const float*)d_in[7];
    const float* bn1  = (const float*)d_in[8];
    const float* Wn2  = (const float*)d_in[9];
    const float* bn2  = (const float*)d_in[10];
    const float* We1  = (const float*)d_in[11];
    const float* be1  = (const float*)d_in[12];
    const float* We2  = (const float*)d_in[13];
    const float* be2  = (const float*)d_in[14];
    const float* Wu1  = (const float*)d_in[15];
    const float* bu1  = (const float*)d_in[16];
    const float* Wu2  = (const float*)d_in[17];
    const float* bu2  = (const float*)d_in[18];
    const float* ln_g = (const float*)d_in[19];
    const float* ln_b = (const float*)d_in[20];
    const float* Wr1  = (const float*)d_in[21];
    const float* br1  = (const float*)d_in[22];
    const float* Wr2  = (const float*)d_in[23];
    const float* br2  = (const float*)d_in[24];
    const float* Ws1  = (const float*)d_in[25];
    const float* bs1  = (const float*)d_in[26];
    const float* Ws2  = (const float*)d_in[27];
    const float* bs2  = (const float*)d_in[28];
    float* out = (float*)d_out;

    // workspace layout (16B-aligned sections)
    int*   deg      = (int*)d_ws;                            // N
    int*   cursor   = deg + N;                               // N
    int*   start    = cursor + N;                            // N
    int*   bsum     = start + N;                             // 512
    int*   csr_col  = bsum + 512;                            // E ints
    float* csr_dist = (float*)(csr_col + E);                 // E floats
    unsigned short* rbf = (unsigned short*)(csr_dist + E);   // E*16 bf16 (51.2 MB)
    float* x0       = (float*)(rbf + (size_t)E * 16);        // N*32 f32
    float* x1       = x0 + (size_t)N * S;                    // N*32 f32
    unsigned short* xb0 = (unsigned short*)(x1 + (size_t)N * S);   // N*32 bf16
    unsigned short* xb1 = xb0 + (size_t)N * S;               // N*32 bf16
    short* wt1      = (short*)(xb1 + (size_t)N * S);         // 5*32*96
    short* wt2      = wt1 + 5 * 32 * 96;                     // 5*32*32
    short* wtu1     = wt2 + 5 * 32 * 32;                     // 5*32*64
    short* wtu2     = wtu1 + 5 * 32 * 64;                    // 5*32*32

    const int egrid = (E + 255) / 256;

    hipMemsetAsync(deg, 0, 2 * N * sizeof(int), stream);   // deg + cursor
    deg_kernel<<<egrid, 256, 0, stream>>>(ei, deg);
    scanA<<<NB, 256, 0, stream>>>(deg, bsum);
    scanB<<<1, 512, 0, stream>>>(bsum);
    scanC<<<NB, 256, 0, stream>>>(deg, bsum, start);
    fill_kernel<<<egrid, 256, 0, stream>>>(ei, pos, start, cursor, csr_col, csr_dist);
    rbf_kernel<<<egrid, 256, 0, stream>>>(csr_dist, rbf);
    prep_wt_kernel<<<60, 256, 0, stream>>>(We1, We2, Wu1, Wu2, wt1, wt2, wtu1, wtu2);

    node_embed_kernel<<<NB, 256, 0, stream>>>(u, v, bno, yf, Wn1, bn1, Wn2, bn2,
                                              x0, xb0);

    float* xin = x0;  float* xout = x1;
    unsigned short* xbin = xb0;  unsigned short* xbout = xb1;
    for (int l = 0; l < L; ++l) {
        layer_kernel<<<LB2, 256, 0, stream>>>(
            deg, start, csr_col, rbf, xin, xbin, xout, xbout,
            wt1 + (size_t)l * 32 * 96,  be1 + (size_t)l * 32,
            wt2 + (size_t)l * 32 * 32,  be2 + (size_t)l * 32,
            wtu1 + (size_t)l * 32 * 64, bu1 + (size_t)l * 32,
            wtu2 + (size_t)l * 32 * 32, bu2 + (size_t)l * 32);
        float* tf = xin; xin = xout; xout = tf;
        unsigned short* tb = xbin; xbin = xbout; xbout = tb;
    }

    final_kernel<<<NB, 256, 0, stream>>>(xin, u, v, ln_g, ln_b,
                                         Wr1, br1, Wr2, br2,
                                         Ws1, bs1, Ws2, bs2, out);
}